// Round 6
// baseline (458.936 us; speedup 1.0000x reference)
//
#include <hip/hip_runtime.h>
#include <cstdint>

// Shapes fixed by the harness:
// u, delta, z: (b=2, d=1024, l=2048) fp32; A: (d, n=16); B, C: (b, n, l); D: (d,)
constexpr int kD = 1024;
constexpr int kN = 16;
constexpr int kL = 2048;
constexpr int BLOCK = 1024;        // one row per block; wave w = state w
constexpr int TPL = kL / 64;       // 32 timesteps per lane
constexpr float LOG2E = 1.44269504088896340736f;

// LDS layouts (skewed to make 64-lane accesses 2-way aliased = free):
//   spdu: (sp,du) pairs; timestep t -> row r=t/32, col c=t%32; float offset r*66 + 2c
//   y   : timestep t -> float offset r*34 + c
constexpr int SPDU_STRIDE = 66;    // 32 pairs + 2 pad floats
constexpr int Y_STRIDE    = 34;    // 32 floats + 2 pad

__device__ __forceinline__ float fast_exp2(float x) { return __builtin_amdgcn_exp2f(x); }
__device__ __forceinline__ float fast_exp(float x)  { return __builtin_amdgcn_exp2f(x * LOG2E); }
__device__ __forceinline__ float softplus_f(float x) {
  return (x > 20.0f) ? x : __logf(1.0f + fast_exp(x));
}

// Single-arg launch_bounds ONLY (R2/R3: min-waves hints trigger spill cascades).
// (1024) implies a 128-VGPR ceiling: 16 waves/block need 4 waves/SIMD.
__global__ __launch_bounds__(BLOCK)
void selscan_kernel(const float* __restrict__ u,  const float* __restrict__ dl,
                    const float* __restrict__ A,  const float* __restrict__ Bm,
                    const float* __restrict__ Cm, const float* __restrict__ Dv,
                    const float* __restrict__ zm, float* __restrict__ out)
{
  const int row  = blockIdx.x;          // b*kD + d
  const int b    = row >> 10;           // kD = 1024
  const int d    = row & (kD - 1);
  const int tid  = threadIdx.x;
  const int lane = tid & 63;
  const int n    = tid >> 6;            // wave id == state index

  __shared__ float spdu[64 * SPDU_STRIDE];   // 16.9 KB
  __shared__ float ylds[64 * Y_STRIDE];      //  8.7 KB

  const size_t roff = (size_t)row * kL;

  // ---- Phase 0: sp/du for 2 timesteps per thread -> LDS; zero y buffer
  {
    const int t = tid * 2;
    float2 uv = reinterpret_cast<const float2*>(u  + roff)[tid];
    float2 dv = reinterpret_cast<const float2*>(dl + roff)[tid];
    float sp0 = softplus_f(dv.x), sp1 = softplus_f(dv.y);
    const int r = t >> 5, c = t & 31;
    float* p = &spdu[r * SPDU_STRIDE + 2 * c];
    p[0] = sp0; p[1] = sp0 * uv.x;
    p[2] = sp1; p[3] = sp1 * uv.y;
    ylds[2 * tid] = 0.0f; ylds[2 * tid + 1] = 0.0f;           // 0..2047
    if (tid < 64) {                                            // 2048..2175
      ylds[2048 + 2 * tid] = 0.0f; ylds[2048 + 2 * tid + 1] = 0.0f;
    }
  }
  __syncthreads();

  // ---- Per-wave constants: this wave's state row of A, B, C
  const float Ar = A[(size_t)d * kN + n] * LOG2E;
  const float4* B4 = reinterpret_cast<const float4*>(Bm + ((size_t)b * kN + n) * kL);
  const float4* C4 = reinterpret_cast<const float4*>(Cm + ((size_t)b * kN + n) * kL);

  // ---- Pass 1: local scan over this lane's 32 contiguous steps.
  // Keep per-step local state hl and prefix-product pp (linearity:
  // h_i = pp_i*h0 + hl_i), so pass 2 needs no exp and no B.
  float hl[TPL], pp[TPL];
  {
    const float* srow = &spdu[lane * SPDU_STRIDE];
    float h = 0.0f, p = 1.0f;
    #pragma unroll
    for (int j = 0; j < 8; ++j) {
      float4 Bv = B4[lane * 8 + j];
      float s0 = srow[8*j+0], d0 = srow[8*j+1];
      float s1 = srow[8*j+2], d1 = srow[8*j+3];
      float s2 = srow[8*j+4], d2 = srow[8*j+5];
      float s3 = srow[8*j+6], d3 = srow[8*j+7];
      float a;
      a = fast_exp2(s0 * Ar); h = a * h + d0 * Bv.x; p *= a; hl[4*j+0] = h; pp[4*j+0] = p;
      a = fast_exp2(s1 * Ar); h = a * h + d1 * Bv.y; p *= a; hl[4*j+1] = h; pp[4*j+1] = p;
      a = fast_exp2(s2 * Ar); h = a * h + d2 * Bv.z; p *= a; hl[4*j+2] = h; pp[4*j+2] = p;
      a = fast_exp2(s3 * Ar); h = a * h + d3 * Bv.w; p *= a; hl[4*j+3] = h; pp[4*j+3] = p;
    }
  }

  // ---- Wave-level scan of chunk aggregates (12 shuffles total per wave).
  // Whole state timeline lives in this one wave: no cross-wave scan at all.
  float h0;
  {
    float cA = pp[TPL-1], cX = hl[TPL-1];
    #pragma unroll
    for (int off = 1; off < 64; off <<= 1) {
      float au = __shfl_up(cA, (unsigned)off, 64);
      float xu = __shfl_up(cX, (unsigned)off, 64);
      bool m = (lane >= off);
      cX = cA * (m ? xu : 0.0f) + cX;
      cA = cA * (m ? au : 1.0f);
    }
    h0 = __shfl_up(cX, 1u, 64);          // exclusive prefix -> state entering chunk
    if (lane == 0) h0 = 0.0f;
  }

  // ---- Pass 2: y_t = C_t * (pp_t*h0 + hl_t), accumulated across the 16
  // state-waves via LDS float atomics (ds_add_f32; 2-way bank alias = free).
  {
    const int ybase = lane * Y_STRIDE;
    #pragma unroll
    for (int j = 0; j < 8; ++j) {
      float4 Cv = C4[lane * 8 + j];
      atomicAdd(&ylds[ybase + 4*j + 0], Cv.x * (pp[4*j+0] * h0 + hl[4*j+0]));
      atomicAdd(&ylds[ybase + 4*j + 1], Cv.y * (pp[4*j+1] * h0 + hl[4*j+1]));
      atomicAdd(&ylds[ybase + 4*j + 2], Cv.z * (pp[4*j+2] * h0 + hl[4*j+2]));
      atomicAdd(&ylds[ybase + 4*j + 3], Cv.w * (pp[4*j+3] * h0 + hl[4*j+3]));
    }
  }
  __syncthreads();

  // ---- Epilogue: 2 timesteps per thread: + u*D, * silu(z), store
  {
    const int t = tid * 2;
    const int r = t >> 5, c = t & 31;
    float y0 = ylds[r * Y_STRIDE + c];
    float y1 = ylds[r * Y_STRIDE + c + 1];
    float2 uv = reinterpret_cast<const float2*>(u  + roff)[tid];
    float2 zv = reinterpret_cast<const float2*>(zm + roff)[tid];
    const float Dd = Dv[d];
    float s0 = 1.0f / (1.0f + fast_exp(-zv.x));
    float s1 = 1.0f / (1.0f + fast_exp(-zv.y));
    float o0 = (y0 + uv.x * Dd) * zv.x * s0;
    float o1 = (y1 + uv.y * Dd) * zv.y * s1;
    reinterpret_cast<float2*>(out + roff)[tid] = make_float2(o0, o1);
  }
}

extern "C" void kernel_launch(void* const* d_in, const int* in_sizes, int n_in,
                              void* d_out, int out_size, void* d_ws, size_t ws_size,
                              hipStream_t stream)
{
  const float* u  = (const float*)d_in[0];
  const float* dl = (const float*)d_in[1];
  const float* A  = (const float*)d_in[2];
  const float* Bm = (const float*)d_in[3];
  const float* Cm = (const float*)d_in[4];
  const float* Dv = (const float*)d_in[5];
  const float* zm = (const float*)d_in[6];
  float* out = (float*)d_out;
  const int rows = in_sizes[0] / kL;   // b*d = 2048
  selscan_kernel<<<rows, BLOCK, 0, stream>>>(u, dl, A, Bm, Cm, Dv, zm, out);
}

// Round 8
// 172.451 us; speedup vs baseline: 2.6613x; 2.6613x over previous
//
#include <hip/hip_runtime.h>
#include <cstdint>

// Shapes fixed by the harness:
// u, delta, z: (b=2, d=1024, l=2048) fp32; A: (d, n=16); B, C: (b, n, l); D: (d,)
constexpr int kD = 1024;
constexpr int kN = 16;
constexpr int kL = 2048;
constexpr int BLOCK = 256;       // 4 waves; each wave owns 4 states over full L
constexpr int TPL = 32;          // timesteps per lane (64 lanes x 32 = 2048)
constexpr int SPW = 4;           // states per wave
constexpr int YSTR = 2112;       // per-wave y slab stride = 64*33 (R7 bug: 2052
                                 // overflowed -- max offset is 33*63+31 = 2110)
constexpr float LOG2E = 1.44269504088896340736f;

__device__ __forceinline__ float fast_exp2(float x) { return __builtin_amdgcn_exp2f(x); }
__device__ __forceinline__ float fast_exp(float x)  { return __builtin_amdgcn_exp2f(x * LOG2E); }
__device__ __forceinline__ float softplus_f(float x) {
  return (x > 20.0f) ? x : __logf(1.0f + fast_exp(x));
}

// Single-arg launch_bounds ONLY. Hard rule from R2/R3/R6: any effective VGPR
// cap <~150 (min-waves hint, or 1024-thread block's implied 128 cap) triggers
// a spill cascade (VGPR 48-64, VALUBusy <6%). 256 threads -> 256-reg ceiling.
__global__ __launch_bounds__(BLOCK)
void selscan_kernel(const float* __restrict__ u,  const float* __restrict__ dl,
                    const float* __restrict__ A,  const float* __restrict__ Bm,
                    const float* __restrict__ Cm, const float* __restrict__ Dv,
                    const float* __restrict__ zm, float* __restrict__ out)
{
  const int row  = blockIdx.x;          // b*kD + d
  const int b    = row >> 10;           // kD = 1024
  const int d    = row & (kD - 1);
  const int tid  = threadIdx.x;
  const int lane = tid & 63;
  const int wid  = tid >> 6;

  __shared__ float ylds[4 * YSTR];      // 33.8 KB; wave-private slabs, skewed

  const size_t roff = (size_t)row * kL;
  const float4* u4 = reinterpret_cast<const float4*>(u  + roff);
  const float4* d4 = reinterpret_cast<const float4*>(dl + roff);

  // ---- Per-lane chunk [32*lane, 32*lane+32): softplus(delta), delta*u in regs.
  // (All 4 waves load the same u/delta: 4x redundant but L1-hot; avoids an
  // LDS round-trip + barrier.)
  float sp[TPL], du[TPL];
  #pragma unroll
  for (int j = 0; j < 8; ++j) {
    float4 uv = u4[lane * 8 + j];
    float4 dv = d4[lane * 8 + j];
    float us[4] = {uv.x, uv.y, uv.z, uv.w};
    float ds[4] = {dv.x, dv.y, dv.z, dv.w};
    #pragma unroll
    for (int k = 0; k < 4; ++k) {
      float s = softplus_f(ds[k]);
      sp[4*j+k] = s;
      du[4*j+k] = s * us[k];
    }
  }

  float y[TPL];
  #pragma unroll
  for (int i = 0; i < TPL; ++i) y[i] = 0.0f;

  const float* Arow = A + (size_t)d * kN;

  // ---- 4 states sequentially (live set stays ~sp+du+y+cp = 128 regs).
  // Linearity trick: h_i = pp_i*h0 + hl_i. Accumulate C_i*hl_i during the
  // local pass and keep cp_i = C_i*pp_i; after the scan add cp_i*h0.
  // => exp computed ONCE per (t,n); B and C read ONCE.
  #pragma unroll 1
  for (int s = 0; s < SPW; ++s) {
    const int n = wid * SPW + s;
    const float Ar = Arow[n] * LOG2E;
    const float4* B4 = reinterpret_cast<const float4*>(Bm + ((size_t)b * kN + n) * kL);
    const float4* C4 = reinterpret_cast<const float4*>(Cm + ((size_t)b * kN + n) * kL);

    float cp[TPL];
    float h = 0.0f, p = 1.0f;
    #pragma unroll 2
    for (int j = 0; j < 8; ++j) {
      float4 Bv = B4[lane * 8 + j];
      float4 Cv = C4[lane * 8 + j];
      float Bs[4] = {Bv.x, Bv.y, Bv.z, Bv.w};
      float Cs[4] = {Cv.x, Cv.y, Cv.z, Cv.w};
      #pragma unroll
      for (int k = 0; k < 4; ++k) {
        const int i = 4*j + k;
        float a = fast_exp2(sp[i] * Ar);
        h = a * h + du[i] * Bs[k];
        p *= a;
        y[i] += Cs[k] * h;     // local-part contribution
        cp[i] = Cs[k] * p;     // h0-correction coefficient
      }
    }

    // ---- Wave-level scan of chunk aggregates (12 shuffles per state).
    float cA = p, cX = h;
    #pragma unroll
    for (int off = 1; off < 64; off <<= 1) {
      float au = __shfl_up(cA, (unsigned)off, 64);
      float xu = __shfl_up(cX, (unsigned)off, 64);
      bool m = (lane >= off);
      cX = cA * (m ? xu : 0.0f) + cX;
      cA = cA * (m ? au : 1.0f);
    }
    float h0 = __shfl_up(cX, 1u, 64);   // exclusive -> state entering chunk
    if (lane == 0) h0 = 0.0f;

    #pragma unroll
    for (int i = 0; i < TPL; ++i) y[i] += cp[i] * h0;
  }

  // ---- Cross-wave y reduction via wave-private skewed slabs (no atomics).
  // Write: addr = wid*YSTR + 33*lane + i -> at fixed i, bank (lane+i)%32:
  // exactly 2-way aliasing across 64 lanes = free (m136).
  {
    float* slab = &ylds[wid * YSTR + 33 * lane];
    #pragma unroll
    for (int i = 0; i < TPL; ++i) slab[i] = y[i];
  }
  __syncthreads();

  // ---- Epilogue: 8 timesteps per thread: sum 4 waves, + u*D, * silu(z), store.
  const float Dd = Dv[d];
  const float4* z4 = reinterpret_cast<const float4*>(zm + roff);
  float acc[8];
  #pragma unroll
  for (int r = 0; r < 8; ++r) {
    const int t = tid * 8 + r;
    const int base = 33 * (t >> 5) + (t & 31);
    float v = ylds[0 * YSTR + base];
    v += ylds[1 * YSTR + base];
    v += ylds[2 * YSTR + base];
    v += ylds[3 * YSTR + base];
    acc[r] = v;
  }
  float4 ua = u4[tid * 2], ub = u4[tid * 2 + 1];
  float4 za = z4[tid * 2], zb = z4[tid * 2 + 1];
  float us[8] = {ua.x, ua.y, ua.z, ua.w, ub.x, ub.y, ub.z, ub.w};
  float zs[8] = {za.x, za.y, za.z, za.w, zb.x, zb.y, zb.z, zb.w};
  float ov[8];
  #pragma unroll
  for (int r = 0; r < 8; ++r) {
    float yy  = acc[r] + us[r] * Dd;
    float sig = 1.0f / (1.0f + fast_exp(-zs[r]));
    ov[r] = yy * zs[r] * sig;
  }
  float4* out4 = reinterpret_cast<float4*>(out + roff);
  out4[tid * 2]     = make_float4(ov[0], ov[1], ov[2], ov[3]);
  out4[tid * 2 + 1] = make_float4(ov[4], ov[5], ov[6], ov[7]);
}

extern "C" void kernel_launch(void* const* d_in, const int* in_sizes, int n_in,
                              void* d_out, int out_size, void* d_ws, size_t ws_size,
                              hipStream_t stream)
{
  const float* u  = (const float*)d_in[0];
  const float* dl = (const float*)d_in[1];
  const float* A  = (const float*)d_in[2];
  const float* Bm = (const float*)d_in[3];
  const float* Cm = (const float*)d_in[4];
  const float* Dv = (const float*)d_in[5];
  const float* zm = (const float*)d_in[6];
  float* out = (float*)d_out;
  const int rows = in_sizes[0] / kL;   // b*d = 2048
  selscan_kernel<<<rows, BLOCK, 0, stream>>>(u, dl, A, Bm, Cm, Dv, zm, out);
}

// Round 9
// 140.131 us; speedup vs baseline: 3.2751x; 1.2306x over previous
//
#include <hip/hip_runtime.h>
#include <cstdint>

// Shapes fixed by the harness:
// u, delta, z: (b=2, d=1024, l=2048) fp32; A: (d, n=16); B, C: (b, n, l); D: (d,)
constexpr int kD = 1024;
constexpr int kN = 16;
constexpr int kL = 2048;
constexpr int BLOCK = 512;
constexpr int T  = kL / BLOCK;   // 4 timesteps per thread (one float4)
constexpr int NW = BLOCK / 64;   // 8 waves per block
constexpr int NH = 8;            // states per half (kN/2)
constexpr float LOG2E = 1.44269504088896340736f;

__device__ __forceinline__ float fast_exp2(float x) { return __builtin_amdgcn_exp2f(x); }
__device__ __forceinline__ float fast_exp(float x)  { return __builtin_amdgcn_exp2f(x * LOG2E); }
__device__ __forceinline__ float softplus_f(float x) {
  return (x > 20.0f) ? x : __logf(1.0f + fast_exp(x));
}

// DPP move: result = valid&row-enabled ? src[shifted lane] : old.
// All scan steps use combine-identity as 'old' so masked lanes are no-ops.
template<int CTRL, int RM>
__device__ __forceinline__ float dppf(float old_, float src) {
  union U { float f; int i; };
  U o, s, r; o.f = old_; s.f = src;
  r.i = __builtin_amdgcn_update_dpp(o.i, s.i, CTRL, RM, 0xF, false);
  return r.f;
}

// Composed inclusive scan of (a,x) over 64 lanes, entirely on the VALU pipe
// (gfx9 DPP: row_shr 0x111/0x112/0x114/0x118, row_bcast15 0x142 rows{1,3},
// row_bcast31 0x143 rows{2,3}). Combine: (a1,x1)*(a2,x2) = (a1*a2, a2*x1+x2).
__device__ __forceinline__ void wave_scan(float& a, float& x) {
  { float as = dppf<0x111,0xF>(1.0f,a); float xs = dppf<0x111,0xF>(0.0f,x); x = a*xs + x; a = as*a; }
  { float as = dppf<0x112,0xF>(1.0f,a); float xs = dppf<0x112,0xF>(0.0f,x); x = a*xs + x; a = as*a; }
  { float as = dppf<0x114,0xF>(1.0f,a); float xs = dppf<0x114,0xF>(0.0f,x); x = a*xs + x; a = as*a; }
  { float as = dppf<0x118,0xF>(1.0f,a); float xs = dppf<0x118,0xF>(0.0f,x); x = a*xs + x; a = as*a; }
  { float as = dppf<0x142,0xA>(1.0f,a); float xs = dppf<0x142,0xA>(0.0f,x); x = a*xs + x; a = as*a; }
  { float as = dppf<0x143,0xC>(1.0f,a); float xs = dppf<0x143,0xC>(0.0f,x); x = a*xs + x; a = as*a; }
}

// Single-arg launch_bounds ONLY: any min-waves hint triggers a spill cascade
// (R2: 48 VGPR + 350 MB scratch; R3: 64 VGPR + 260 MB; R6: 1024-thr cap).
__global__ __launch_bounds__(BLOCK)
void selscan_kernel(const float* __restrict__ u,  const float* __restrict__ dl,
                    const float* __restrict__ A,  const float* __restrict__ Bm,
                    const float* __restrict__ Cm, const float* __restrict__ Dv,
                    const float* __restrict__ zm, float* __restrict__ out)
{
  const int row  = blockIdx.x;          // b*kD + d
  const int b    = row >> 10;           // kD = 1024
  const int d    = row & (kD - 1);
  const int tid  = threadIdx.x;
  const int lane = tid & 63;
  const int wid  = tid >> 6;

  const size_t roff = (size_t)row * kL;
  const float4* u4 = reinterpret_cast<const float4*>(u  + roff);
  const float4* d4 = reinterpret_cast<const float4*>(dl + roff);

  // Per-thread chunk [tid*T, tid*T+T): u, softplus(delta), delta*u in regs.
  float uu[T], sp[T], du[T];
  {
    float4 a0 = u4[tid];
    uu[0]=a0.x; uu[1]=a0.y; uu[2]=a0.z; uu[3]=a0.w;
    float4 b0 = d4[tid];
    float dv[T] = {b0.x, b0.y, b0.z, b0.w};
    #pragma unroll
    for (int i = 0; i < T; ++i) { sp[i] = softplus_f(dv[i]); du[i] = sp[i] * uu[i]; }
  }

  float y[T];
  #pragma unroll
  for (int i = 0; i < T; ++i) y[i] = 0.0f;

  __shared__ float sA[NW][NH], sX[NW][NH], eX[NW][NH];

  #pragma unroll 1                      // halves sequential: live-range control
  for (int half = 0; half < 2; ++half) {
    float Ar[NH];
    {
      const float4* A4 = reinterpret_cast<const float4*>(A + (size_t)d * kN + half * NH);
      float4 v0 = A4[0], v1 = A4[1];
      Ar[0]=v0.x*LOG2E; Ar[1]=v0.y*LOG2E; Ar[2]=v0.z*LOG2E; Ar[3]=v0.w*LOG2E;
      Ar[4]=v1.x*LOG2E; Ar[5]=v1.y*LOG2E; Ar[6]=v1.z*LOG2E; Ar[7]=v1.w*LOG2E;
    }
    const float4* B4 = reinterpret_cast<const float4*>(Bm + ((size_t)b * kN + half * NH) * kL);
    const float4* C4 = reinterpret_cast<const float4*>(Cm + ((size_t)b * kN + half * NH) * kL);

    // ---- Pass A: local scan from zero; keep hl (local state) and pp
    // (prefix product) live: h_i = pp_i*h0 + hl_i (linearity).
    float hl[NH][T], pp[NH][T];
    #pragma unroll
    for (int n = 0; n < NH; ++n) {
      float4 b0 = B4[n*(kL/4) + tid];
      float Bv[T] = {b0.x, b0.y, b0.z, b0.w};
      float h = 0.0f, p = 1.0f;
      #pragma unroll
      for (int i = 0; i < T; ++i) {
        float a = fast_exp2(sp[i] * Ar[n]);
        h = a * h + du[i] * Bv[i];
        p *= a;
        hl[n][i] = h; pp[n][i] = p;
      }
    }

    // ---- C loads issued before the scan: scan hides their L2 latency.
    float4 cv[NH];
    #pragma unroll
    for (int n = 0; n < NH; ++n) cv[n] = C4[n*(kL/4) + tid];

    // ---- Wave-level scan on chunk aggregates — DPP, zero DS-pipe ops.
    float cA[NH], cX[NH];
    #pragma unroll
    for (int n = 0; n < NH; ++n) { cA[n] = pp[n][T-1]; cX[n] = hl[n][T-1]; }
    #pragma unroll
    for (int n = 0; n < NH; ++n) wave_scan(cA[n], cX[n]);

    // ---- Cross-wave scan (8 waves) through LDS (tiny DS traffic).
    if (lane == 63) {
      #pragma unroll
      for (int n = 0; n < NH; ++n) { sA[wid][n] = cA[n]; sX[wid][n] = cX[n]; }
    }
    __syncthreads();
    if (tid < NH) {
      const int n = tid;
      float x = 0.0f;
      #pragma unroll
      for (int w = 0; w < NW; ++w) {
        eX[w][n] = x;                    // exclusive x-prefix for wave w
        x = sA[w][n] * x + sX[w][n];
      }
    }
    __syncthreads();

    // ---- Apply: h_i = pp_i*h0 + hl_i;  y_i += C_i*h_i   (no loads, no exp)
    #pragma unroll
    for (int n = 0; n < NH; ++n) {
      // lane-exclusive prefix via wave_shr:1 (0x138); lane0 gets identity old.
      float al = dppf<0x138,0xF>(1.0f, cA[n]);
      float xl = dppf<0x138,0xF>(0.0f, cX[n]);
      float h0 = al * eX[wid][n] + xl;   // state entering this thread's chunk

      float Cv[T] = {cv[n].x, cv[n].y, cv[n].z, cv[n].w};
      #pragma unroll
      for (int i = 0; i < T; ++i) {
        float h = pp[n][i] * h0 + hl[n][i];
        y[i] += Cv[i] * h;
      }
    }
    __syncthreads();   // protect sA/sX/eX reuse across halves
  }

  // ---- Epilogue: + u*D, * silu(z), store  (uu kept in regs)
  const float Dd = Dv[d];
  const float4* z4 = reinterpret_cast<const float4*>(zm + roff);
  float4 z0 = z4[tid];
  float zv[T] = {z0.x, z0.y, z0.z, z0.w};
  float ov[T];
  #pragma unroll
  for (int i = 0; i < T; ++i) {
    float yy  = y[i] + uu[i] * Dd;
    float sig = 1.0f / (1.0f + fast_exp(-zv[i]));
    ov[i] = yy * zv[i] * sig;
  }
  reinterpret_cast<float4*>(out + roff)[tid] = make_float4(ov[0], ov[1], ov[2], ov[3]);
}

extern "C" void kernel_launch(void* const* d_in, const int* in_sizes, int n_in,
                              void* d_out, int out_size, void* d_ws, size_t ws_size,
                              hipStream_t stream)
{
  const float* u  = (const float*)d_in[0];
  const float* dl = (const float*)d_in[1];
  const float* A  = (const float*)d_in[2];
  const float* Bm = (const float*)d_in[3];
  const float* Cm = (const float*)d_in[4];
  const float* Dv = (const float*)d_in[5];
  const float* zm = (const float*)d_in[6];
  float* out = (float*)d_out;
  const int rows = in_sizes[0] / kL;   // b*d = 2048
  selscan_kernel<<<rows, BLOCK, 0, stream>>>(u, dl, A, Bm, Cm, Dv, zm, out);
}

// Round 10
// 138.240 us; speedup vs baseline: 3.3199x; 1.0137x over previous
//
#include <hip/hip_runtime.h>
#include <cstdint>

// Shapes fixed by the harness:
// u, delta, z: (b=2, d=1024, l=2048) fp32; A: (d, n=16); B, C: (b, n, l); D: (d,)
constexpr int kD = 1024;
constexpr int kN = 16;
constexpr int kL = 2048;
constexpr int BLOCK = 512;
constexpr int T  = kL / BLOCK;   // 4 timesteps per thread (one float4)
constexpr int NW = BLOCK / 64;   // 8 waves per block
constexpr int NH = 8;            // states per half (kN/2)
constexpr float LOG2E = 1.44269504088896340736f;

__device__ __forceinline__ float fast_exp2(float x) { return __builtin_amdgcn_exp2f(x); }
__device__ __forceinline__ float fast_exp(float x)  { return __builtin_amdgcn_exp2f(x * LOG2E); }
__device__ __forceinline__ float softplus_f(float x) {
  return (x > 20.0f) ? x : __logf(1.0f + fast_exp(x));
}

// DPP move: result = valid&row-enabled ? src[shifted lane] : old.
// Scan steps pass the combine identity as 'old' so masked lanes are no-ops.
template<int CTRL, int RM>
__device__ __forceinline__ float dppf(float old_, float src) {
  union U { float f; int i; };
  U o, s, r; o.f = old_; s.f = src;
  r.i = __builtin_amdgcn_update_dpp(o.i, s.i, CTRL, RM, 0xF, false);
  return r.f;
}

// 64-lane inclusive scan of (a,x) entirely on the VALU pipe (gfx9 DPP:
// row_shr 1/2/4/8, row_bcast15 rows{1,3}, row_bcast31 rows{2,3}).
// Combine: (a1,x1)*(a2,x2) = (a1*a2, a2*x1+x2).  [R9: -20 us vs ds_bpermute]
__device__ __forceinline__ void wave_scan(float& a, float& x) {
  { float as = dppf<0x111,0xF>(1.0f,a); float xs = dppf<0x111,0xF>(0.0f,x); x = a*xs + x; a = as*a; }
  { float as = dppf<0x112,0xF>(1.0f,a); float xs = dppf<0x112,0xF>(0.0f,x); x = a*xs + x; a = as*a; }
  { float as = dppf<0x114,0xF>(1.0f,a); float xs = dppf<0x114,0xF>(0.0f,x); x = a*xs + x; a = as*a; }
  { float as = dppf<0x118,0xF>(1.0f,a); float xs = dppf<0x118,0xF>(0.0f,x); x = a*xs + x; a = as*a; }
  { float as = dppf<0x142,0xA>(1.0f,a); float xs = dppf<0x142,0xA>(0.0f,x); x = a*xs + x; a = as*a; }
  { float as = dppf<0x143,0xC>(1.0f,a); float xs = dppf<0x143,0xC>(0.0f,x); x = a*xs + x; a = as*a; }
}

// Single-arg launch_bounds ONLY: any min-waves hint triggers a spill cascade
// (R2: 48 VGPR + 350 MB scratch; R3: 64 VGPR + 260 MB; R6: 1024-thr cap).
__global__ __launch_bounds__(BLOCK)
void selscan_kernel(const float* __restrict__ u,  const float* __restrict__ dl,
                    const float* __restrict__ A,  const float* __restrict__ Bm,
                    const float* __restrict__ Cm, const float* __restrict__ Dv,
                    const float* __restrict__ zm, float* __restrict__ out)
{
  const int row  = blockIdx.x;          // b*kD + d
  const int b    = row >> 10;           // kD = 1024
  const int d    = row & (kD - 1);
  const int tid  = threadIdx.x;
  const int lane = tid & 63;
  const int wid  = tid >> 6;

  const size_t roff = (size_t)row * kL;
  const float4* u4 = reinterpret_cast<const float4*>(u  + roff);
  const float4* d4 = reinterpret_cast<const float4*>(dl + roff);

  // Per-thread chunk [tid*T, tid*T+T): u, softplus(delta), delta*u in regs.
  float uu[T], sp[T], du[T];
  {
    float4 a0 = u4[tid];
    uu[0]=a0.x; uu[1]=a0.y; uu[2]=a0.z; uu[3]=a0.w;
    float4 b0 = d4[tid];
    float dv[T] = {b0.x, b0.y, b0.z, b0.w};
    #pragma unroll
    for (int i = 0; i < T; ++i) { sp[i] = softplus_f(dv[i]); du[i] = sp[i] * uu[i]; }
  }

  float y[T];
  #pragma unroll
  for (int i = 0; i < T; ++i) y[i] = 0.0f;

  __shared__ float sA[NW][NH], sX[NW][NH], eX[NW][NH];

  #pragma unroll 1                      // halves sequential: live-range control
  for (int half = 0; half < 2; ++half) {
    float Ar[NH];
    {
      const float4* A4 = reinterpret_cast<const float4*>(A + (size_t)d * kN + half * NH);
      float4 v0 = A4[0], v1 = A4[1];
      Ar[0]=v0.x*LOG2E; Ar[1]=v0.y*LOG2E; Ar[2]=v0.z*LOG2E; Ar[3]=v0.w*LOG2E;
      Ar[4]=v1.x*LOG2E; Ar[5]=v1.y*LOG2E; Ar[6]=v1.z*LOG2E; Ar[7]=v1.w*LOG2E;
    }
    const float4* B4 = reinterpret_cast<const float4*>(Bm + ((size_t)b * kN + half * NH) * kL);
    const float4* C4 = reinterpret_cast<const float4*>(Cm + ((size_t)b * kN + half * NH) * kL);

    // ---- Pass A with the cp-trick: C is CONSUMED at load time.
    // h_i = pp_i*h0 + hl_i (linearity) =>
    //   y_i += C_i*hl_i   accumulated here,
    //   cp_i = C_i*pp_i   saved (32 regs; replaces hl+pp's 64 and cv's 32),
    // so the post-scan apply is pure register FMA — nothing to sink/stall.
    float cp[NH][T];
    float cA[NH], cX[NH];
    #pragma unroll
    for (int n = 0; n < NH; ++n) {
      float4 b0 = B4[n*(kL/4) + tid];
      float4 c0 = C4[n*(kL/4) + tid];
      float Bv[T] = {b0.x, b0.y, b0.z, b0.w};
      float Cv[T] = {c0.x, c0.y, c0.z, c0.w};
      float h = 0.0f, p = 1.0f;
      #pragma unroll
      for (int i = 0; i < T; ++i) {
        float a = fast_exp2(sp[i] * Ar[n]);
        h = a * h + du[i] * Bv[i];
        p *= a;
        y[i] += Cv[i] * h;
        cp[n][i] = Cv[i] * p;
      }
      cA[n] = p; cX[n] = h;
    }

    // ---- Wave-level scan on chunk aggregates — DPP, zero DS-pipe ops.
    #pragma unroll
    for (int n = 0; n < NH; ++n) wave_scan(cA[n], cX[n]);

    // ---- Cross-wave scan (8 waves) through LDS (tiny DS traffic).
    if (lane == 63) {
      #pragma unroll
      for (int n = 0; n < NH; ++n) { sA[wid][n] = cA[n]; sX[wid][n] = cX[n]; }
    }
    __syncthreads();
    if (tid < NH) {
      const int n = tid;
      float x = 0.0f;
      #pragma unroll
      for (int w = 0; w < NW; ++w) {
        eX[w][n] = x;                    // exclusive x-prefix for wave w
        x = sA[w][n] * x + sX[w][n];
      }
    }
    __syncthreads();

    // ---- Apply: y_i += cp_i * h0   (pure FMA from registers)
    #pragma unroll
    for (int n = 0; n < NH; ++n) {
      // lane-exclusive prefix via wave_shr:1; lane0 gets the identity old.
      float al = dppf<0x138,0xF>(1.0f, cA[n]);
      float xl = dppf<0x138,0xF>(0.0f, cX[n]);
      float h0 = al * eX[wid][n] + xl;   // state entering this thread's chunk
      #pragma unroll
      for (int i = 0; i < T; ++i) y[i] += cp[n][i] * h0;
    }
    __syncthreads();   // protect sA/sX/eX reuse across halves
  }

  // ---- Epilogue: + u*D, * silu(z), store  (uu kept in regs)
  const float Dd = Dv[d];
  const float4* z4 = reinterpret_cast<const float4*>(zm + roff);
  float4 z0 = z4[tid];
  float zv[T] = {z0.x, z0.y, z0.z, z0.w};
  float ov[T];
  #pragma unroll
  for (int i = 0; i < T; ++i) {
    float yy  = y[i] + uu[i] * Dd;
    float sig = 1.0f / (1.0f + fast_exp(-zv[i]));
    ov[i] = yy * zv[i] * sig;
  }
  reinterpret_cast<float4*>(out + roff)[tid] = make_float4(ov[0], ov[1], ov[2], ov[3]);
}

extern "C" void kernel_launch(void* const* d_in, const int* in_sizes, int n_in,
                              void* d_out, int out_size, void* d_ws, size_t ws_size,
                              hipStream_t stream)
{
  const float* u  = (const float*)d_in[0];
  const float* dl = (const float*)d_in[1];
  const float* A  = (const float*)d_in[2];
  const float* Bm = (const float*)d_in[3];
  const float* Cm = (const float*)d_in[4];
  const float* Dv = (const float*)d_in[5];
  const float* zm = (const float*)d_in[6];
  float* out = (float*)d_out;
  const int rows = in_sizes[0] / kL;   // b*d = 2048
  selscan_kernel<<<rows, BLOCK, 0, stream>>>(u, dl, A, Bm, Cm, Dv, zm, out);
}